// Round 1
// baseline (465.481 us; speedup 1.0000x reference)
//
#include <hip/hip_runtime.h>

typedef unsigned short u16;
typedef unsigned int u32;
typedef __bf16 bf16x8 __attribute__((ext_vector_type(8)));
typedef float f32x4 __attribute__((ext_vector_type(4)));

__device__ __forceinline__ u16 f2b(float f) {
  u32 u = __float_as_uint(f);
  return (u16)((u + 0x7FFFu + ((u >> 16) & 1u)) >> 16);
}
__device__ __forceinline__ float b2f(u16 v) { return __uint_as_float((u32)v << 16); }
__device__ __forceinline__ float sumsq2(u32 u) {
  float lo = __uint_as_float(u << 16);
  float hi = __uint_as_float(u & 0xFFFF0000u);
  return lo * lo + hi * hi;
}
__device__ __forceinline__ void gl2lds16(const void* g, void* l) {
  __builtin_amdgcn_global_load_lds((__attribute__((address_space(1))) void*)g,
                                   (__attribute__((address_space(3))) void*)l, 16, 0, 0);
}

// ---------- fp32 -> bf16 transposed weight: Wt[n][k] = W[k][n] ----------
__global__ __launch_bounds__(256) void k_wtrans(const float* __restrict__ W,
                                                u16* __restrict__ Wt) {
  __shared__ float sm[64 * 65];
  const int r0 = blockIdx.y * 64, c0 = blockIdx.x * 64;
  const int tid = threadIdx.x;
#pragma unroll
  for (int i = 0; i < 16; ++i) {
    int idx = i * 256 + tid;
    int r = idx >> 6, c = idx & 63;
    sm[c * 65 + r] = W[(size_t)(r0 + r) * 1024 + c0 + c];
  }
  __syncthreads();
#pragma unroll
  for (int i = 0; i < 16; ++i) {
    int idx = i * 256 + tid;
    int r = idx >> 6, c = idx & 63;
    Wt[(size_t)(c0 + r) * 1024 + r0 + c] = f2b(sm[r * 65 + c]);
  }
}

// ---------- layernorm fp32 -> bf16 ----------
__global__ __launch_bounds__(256) void k_ln(const float* __restrict__ x,
                                            const float* __restrict__ w,
                                            const float* __restrict__ bb,
                                            u16* __restrict__ y) {
  const int row = blockIdx.x;
  const int tid = threadIdx.x;
  const float4 v = ((const float4*)(x + (size_t)row * 1024))[tid];
  float s = v.x + v.y + v.z + v.w;
  float s2 = v.x * v.x + v.y * v.y + v.z * v.z + v.w * v.w;
  for (int o = 32; o > 0; o >>= 1) {
    s += __shfl_down(s, o);
    s2 += __shfl_down(s2, o);
  }
  __shared__ float red[8];
  const int wave = tid >> 6;
  if ((tid & 63) == 0) { red[wave * 2] = s; red[wave * 2 + 1] = s2; }
  __syncthreads();
  s = red[0] + red[2] + red[4] + red[6];
  s2 = red[1] + red[3] + red[5] + red[7];
  const float mu = s * (1.0f / 1024.0f);
  const float var = s2 * (1.0f / 1024.0f) - mu * mu;
  const float rs = rsqrtf(var + 1e-5f);
  const float4 wv = ((const float4*)w)[tid];
  const float4 bv = ((const float4*)bb)[tid];
  u16* yr = y + (size_t)row * 1024 + tid * 4;
  yr[0] = f2b((v.x - mu) * rs * wv.x + bv.x);
  yr[1] = f2b((v.y - mu) * rs * wv.y + bv.y);
  yr[2] = f2b((v.z - mu) * rs * wv.z + bv.z);
  yr[3] = f2b((v.w - mu) * rs * wv.w + bv.w);
}

// ---------- per-head sum of squares of qk rows (token path) ----------
// q2[(b*16+h)*1024 + n] = sum_d qk[b,n,h*64+d]^2
__global__ __launch_bounds__(256) void k_q2(const u16* __restrict__ qk,
                                            float* __restrict__ q2) {
  const int row = blockIdx.x * 4 + (threadIdx.x >> 6);
  const int lane = threadIdx.x & 63;
  const u16* p = qk + (size_t)row * 1024 + lane * 16;
  const uint4 a = *(const uint4*)p;
  const uint4 b = *(const uint4*)(p + 8);
  float s = sumsq2(a.x) + sumsq2(a.y) + sumsq2(a.z) + sumsq2(a.w) +
            sumsq2(b.x) + sumsq2(b.y) + sumsq2(b.z) + sumsq2(b.w);
  s += __shfl_down(s, 1, 4);
  s += __shfl_down(s, 2, 4);
  if ((lane & 3) == 0) {
    const int h = lane >> 2;
    const int bidx = row >> 10, n = row & 1023;
    q2[((size_t)(bidx * 16 + h)) * 1024 + n] = s;
  }
}

// ---------- full-row sum of squares (channel path, on qkcT rows) ----------
__global__ __launch_bounds__(256) void k_rowsq(const u16* __restrict__ M,
                                               float* __restrict__ out) {
  const int row = blockIdx.x * 4 + (threadIdx.x >> 6);
  const int lane = threadIdx.x & 63;
  const u16* p = M + (size_t)row * 1024 + lane * 16;
  const uint4 a = *(const uint4*)p;
  const uint4 b = *(const uint4*)(p + 8);
  float s = sumsq2(a.x) + sumsq2(a.y) + sumsq2(a.z) + sumsq2(a.w) +
            sumsq2(b.x) + sumsq2(b.y) + sumsq2(b.z) + sumsq2(b.w);
  for (int o = 32; o > 0; o >>= 1) s += __shfl_down(s, o);
  if (lane == 0) out[row] = s;
}

// ---------- 128x128-tile bf16 MFMA GEMM core (B^T layout, m97 structure) ----------
__device__ __forceinline__ void gemm_core_128(const u16* __restrict__ Ab,
                                              const u16* __restrict__ Bb,
                                              int lda, int ldb, int K,
                                              u16* sm, f32x4 acc[4][4]) {
  const int tid = threadIdx.x;
  const int wave = tid >> 6;
  const int wr = wave >> 1, wc = wave & 1;
  const int lane = tid & 63;
  const int lc = lane & 15, quad = lane >> 4;
  u16* smA = sm;
  u16* smB = sm + 4096;
  const int sr = tid >> 2, sk = (tid & 3) << 3;
  const u16* gA = Ab + (size_t)sr * lda + sk;
  const u16* gB = Bb + (size_t)sr * ldb + sk;
  const size_t a64 = (size_t)64 * lda, b64 = (size_t)64 * ldb;
  u16* dA = smA + tid * 8;
  u16* dB = smB + tid * 8;
  for (int kt = 0; kt < K; kt += 32) {
    gl2lds16(gA + kt, dA);
    gl2lds16(gA + a64 + kt, dA + 2048);
    gl2lds16(gB + kt, dB);
    gl2lds16(gB + b64 + kt, dB + 2048);
    __syncthreads();
    bf16x8 af[4], bfr[4];
#pragma unroll
    for (int i = 0; i < 4; ++i) {
      af[i] = *(const bf16x8*)(smA + (wr * 64 + i * 16 + lc) * 32 + quad * 8);
      bfr[i] = *(const bf16x8*)(smB + (wc * 64 + i * 16 + lc) * 32 + quad * 8);
    }
#pragma unroll
    for (int i = 0; i < 4; ++i)
#pragma unroll
      for (int j = 0; j < 4; ++j)
        acc[i][j] = __builtin_amdgcn_mfma_f32_16x16x32_bf16(af[i], bfr[j], acc[i][j], 0, 0, 0);
    __syncthreads();
  }
}

// ---------- GEMM, bf16 output in natural row-major ----------
__global__ __launch_bounds__(256) void k_gemm_n(const u16* __restrict__ A,
                                                const u16* __restrict__ Bt,
                                                u16* __restrict__ C,
                                                int lda, int ldb, int ldc, int K) {
  __shared__ u16 sm[8192];
  const int m0 = blockIdx.x * 128, n0 = blockIdx.y * 128;
  f32x4 acc[4][4];
#pragma unroll
  for (int i = 0; i < 4; ++i)
#pragma unroll
    for (int j = 0; j < 4; ++j) acc[i][j] = (f32x4){0.f, 0.f, 0.f, 0.f};
  gemm_core_128(A + (size_t)m0 * lda, Bt + (size_t)n0 * ldb, lda, ldb, K, sm, acc);
  const int tid = threadIdx.x, wave = tid >> 6;
  const int wr = wave >> 1, wc = wave & 1;
  const int lc = tid & 15, quad = (tid & 63) >> 4;
#pragma unroll
  for (int i = 0; i < 4; ++i)
#pragma unroll
    for (int j = 0; j < 4; ++j) {
      const int n = n0 + wc * 64 + j * 16 + lc;
#pragma unroll
      for (int r = 0; r < 4; ++r) {
        const int m = m0 + wr * 64 + i * 16 + quad * 4 + r;
        C[(size_t)m * ldc + n] = f2b(acc[i][j][r]);
      }
    }
}

// ---------- GEMM + residual epilogue: out = res + acc*gamma[n] (fp32) ----------
__global__ __launch_bounds__(256) void k_gemm_res(const u16* __restrict__ A,
                                                  const u16* __restrict__ Bt,
                                                  const float* __restrict__ res,
                                                  const float* __restrict__ gamma,
                                                  float* __restrict__ out) {
  __shared__ u16 sm[8192];
  const int m0 = blockIdx.x * 128, n0 = blockIdx.y * 128;
  f32x4 acc[4][4];
#pragma unroll
  for (int i = 0; i < 4; ++i)
#pragma unroll
    for (int j = 0; j < 4; ++j) acc[i][j] = (f32x4){0.f, 0.f, 0.f, 0.f};
  gemm_core_128(A + (size_t)m0 * 1024, Bt + (size_t)n0 * 1024, 1024, 1024, 1024, sm, acc);
  const int tid = threadIdx.x, wave = tid >> 6;
  const int wr = wave >> 1, wc = wave & 1;
  const int lc = tid & 15, quad = (tid & 63) >> 4;
#pragma unroll
  for (int i = 0; i < 4; ++i)
#pragma unroll
    for (int j = 0; j < 4; ++j) {
      const int n = n0 + wc * 64 + j * 16 + lc;
      const float g = gamma[n];
#pragma unroll
      for (int r = 0; r < 4; ++r) {
        const size_t idx = (size_t)(m0 + wr * 64 + i * 16 + quad * 4 + r) * 1024 + n;
        out[idx] = res[idx] + acc[i][j][r] * g;
      }
    }
}

// ---------- GEMM, bf16 output transposed per batch: outT[(b*1024+n)*1024 + mloc] ----------
__global__ __launch_bounds__(256) void k_gemm_t(const u16* __restrict__ A,
                                                const u16* __restrict__ Bt,
                                                u16* __restrict__ outT) {
  __shared__ u16 sm[8704];
  const int m0 = blockIdx.x * 128, n0 = blockIdx.y * 128;
  f32x4 acc[4][4];
#pragma unroll
  for (int i = 0; i < 4; ++i)
#pragma unroll
    for (int j = 0; j < 4; ++j) acc[i][j] = (f32x4){0.f, 0.f, 0.f, 0.f};
  gemm_core_128(A + (size_t)m0 * 1024, Bt + (size_t)n0 * 1024, 1024, 1024, 1024, sm, acc);
  const int tid = threadIdx.x, wave = tid >> 6;
  const int wr = wave >> 1, wc = wave & 1;
  const int lc = tid & 15, quad = (tid & 63) >> 4;
  const int b = m0 >> 10, mloc = m0 & 1023;
  for (int half = 0; half < 2; ++half) {
    if (wc == half) {
#pragma unroll
      for (int i = 0; i < 4; ++i)
#pragma unroll
        for (int j = 0; j < 4; ++j)
#pragma unroll
          for (int r = 0; r < 4; ++r)
            sm[(j * 16 + lc) * 136 + wr * 64 + i * 16 + quad * 4 + r] = f2b(acc[i][j][r]);
    }
    __syncthreads();
#pragma unroll
    for (int it = 0; it < 4; ++it) {
      const int rr = it * 16 + (tid >> 4);
      const int c8 = (tid & 15) << 3;
      *(uint4*)&outT[((size_t)(b * 1024 + n0 + half * 64 + rr)) * 1024 + mloc + c8] =
          *(const uint4*)&sm[rr * 136 + c8];
    }
    __syncthreads();
  }
}

// ---------- token attention (flash-style, no-max softmax since logits <= 0) ----------
__global__ __launch_bounds__(256) void k_attn(const u16* __restrict__ qk,
                                              const u16* __restrict__ vT,
                                              const float* __restrict__ q2,
                                              const float* __restrict__ tau,
                                              u16* __restrict__ outp) {
  const int q0 = blockIdx.x * 64;
  const int bh = blockIdx.y;
  const int b = bh >> 4, h = bh & 15;
  __shared__ u16 sQ[64 * 72];
  __shared__ u16 sK[128 * 72];
  __shared__ u16 sV[64 * 136];
  __shared__ u16 sP[64 * 136];
  __shared__ float sq2i[64];
  __shared__ float sq2k[128];
  const int tid = threadIdx.x;
  const int wave = tid >> 6;
  const int lane = tid & 63;
  const int lc = lane & 15, quad = lane >> 4;
  const float scale = tau[h] * 0.125f;  // 1/sqrt(64)
  const u16* qkb = qk + (size_t)b * (1024 * 1024) + h * 64;
  const u16* vTb = vT + ((size_t)b * 1024 + h * 64) * 1024;
  {
    const int r = tid >> 2, c = (tid & 3) << 3;
    const u16* g = qkb + (size_t)(q0 + r) * 1024 + c;
    *(uint4*)&sQ[r * 72 + c] = *(const uint4*)g;
    *(uint4*)&sQ[r * 72 + c + 32] = *(const uint4*)(g + 32);
  }
  if (tid < 64) sq2i[tid] = q2[(size_t)bh * 1024 + q0 + tid];
  f32x4 oacc[4];
#pragma unroll
  for (int j = 0; j < 4; ++j) oacc[j] = (f32x4){0.f, 0.f, 0.f, 0.f};
  float rsum[4] = {0.f, 0.f, 0.f, 0.f};

  for (int kt = 0; kt < 8; ++kt) {
#pragma unroll
    for (int i = 0; i < 4; ++i) {
      const int idx = i * 256 + tid;
      const int r = idx >> 3, c = (idx & 7) << 3;
      *(uint4*)&sK[r * 72 + c] = *(const uint4*)(qkb + (size_t)(kt * 128 + r) * 1024 + c);
    }
#pragma unroll
    for (int i = 0; i < 4; ++i) {
      const int idx = i * 256 + tid;
      const int d = idx >> 4, c = (idx & 15) << 3;
      *(uint4*)&sV[d * 136 + c] = *(const uint4*)(vTb + (size_t)d * 1024 + kt * 128 + c);
    }
    if (tid < 128) sq2k[tid] = q2[(size_t)bh * 1024 + kt * 128 + tid];
    __syncthreads();

    const bf16x8 aq0 = *(const bf16x8*)&sQ[(wave * 16 + lc) * 72 + quad * 8];
    const bf16x8 aq1 = *(const bf16x8*)&sQ[(wave * 16 + lc) * 72 + 32 + quad * 8];
    float kps[4] = {0.f, 0.f, 0.f, 0.f};
#pragma unroll
    for (int nb = 0; nb < 8; ++nb) {
      const bf16x8 bk0 = *(const bf16x8*)&sK[(nb * 16 + lc) * 72 + quad * 8];
      const bf16x8 bk1 = *(const bf16x8*)&sK[(nb * 16 + lc) * 72 + 32 + quad * 8];
      f32x4 s = (f32x4){0.f, 0.f, 0.f, 0.f};
      s = __builtin_amdgcn_mfma_f32_16x16x32_bf16(aq0, bk0, s, 0, 0, 0);
      s = __builtin_amdgcn_mfma_f32_16x16x32_bf16(aq1, bk1, s, 0, 0, 0);
      const float q2c = sq2k[nb * 16 + lc];
#pragma unroll
      for (int r = 0; r < 4; ++r) {
        const float e =
            __expf((2.f * s[r] - sq2i[wave * 16 + quad * 4 + r] - q2c) * scale);
        kps[r] += e;
        sP[(wave * 16 + quad * 4 + r) * 136 + nb * 16 + lc] = f2b(e);
      }
    }
#pragma unroll
    for (int r = 0; r < 4; ++r) {
      float p = kps[r];
      p += __shfl_xor(p, 1);
      p += __shfl_xor(p, 2);
      p += __shfl_xor(p, 4);
      p += __shfl_xor(p, 8);
      rsum[r] += p;
    }
    __syncthreads();

    bf16x8 ap[4];
#pragma unroll
    for (int ks = 0; ks < 4; ++ks)
      ap[ks] = *(const bf16x8*)&sP[(wave * 16 + lc) * 136 + ks * 32 + quad * 8];
#pragma unroll
    for (int j2 = 0; j2 < 4; ++j2)
#pragma unroll
      for (int ks = 0; ks < 4; ++ks) {
        const bf16x8 bv = *(const bf16x8*)&sV[(j2 * 16 + lc) * 136 + ks * 32 + quad * 8];
        oacc[j2] = __builtin_amdgcn_mfma_f32_16x16x32_bf16(ap[ks], bv, oacc[j2], 0, 0, 0);
      }
    __syncthreads();
  }
#pragma unroll
  for (int r = 0; r < 4; ++r) {
    const int row = wave * 16 + quad * 4 + r;
    const float inv = 1.f / rsum[r];
    u16* o = outp + ((size_t)(b * 1024 + q0 + row)) * 1024 + h * 64;
#pragma unroll
    for (int j2 = 0; j2 < 4; ++j2) o[j2 * 16 + lc] = f2b(oacc[j2][r] * inv);
  }
}

// ---------- channel attention matrix: A = softmax over d' of scaled (X^T X) ----------
__global__ __launch_bounds__(256) void k_chan_s(const u16* __restrict__ qkcT,
                                                const float* __restrict__ q2c,
                                                const float* __restrict__ tau,
                                                u16* __restrict__ Aout) {
  const int bc = blockIdx.x, b = bc >> 3, c = bc & 7;
  __shared__ u16 sX[8192];
  __shared__ float sq2[128];
  const int tid = threadIdx.x, wave = tid >> 6, lane = tid & 63;
  const int lc = lane & 15, quad = lane >> 4;
  const u16* Xb = qkcT + ((size_t)b * 1024 + c * 128) * 1024;
  if (tid < 128) sq2[tid] = q2c[(size_t)b * 1024 + c * 128 + tid];
  f32x4 acc[2][8];
#pragma unroll
  for (int i = 0; i < 2; ++i)
#pragma unroll
    for (int j = 0; j < 8; ++j) acc[i][j] = (f32x4){0.f, 0.f, 0.f, 0.f};
  for (int nt = 0; nt < 1024; nt += 64) {
#pragma unroll
    for (int i = 0; i < 4; ++i) {
      const int idx = i * 256 + tid;
      gl2lds16(Xb + (size_t)(idx >> 3) * 1024 + nt + ((idx & 7) << 3), sX + idx * 8);
    }
    __syncthreads();
    bf16x8 af[2][2];
#pragma unroll
    for (int i = 0; i < 2; ++i)
#pragma unroll
      for (int ks = 0; ks < 2; ++ks)
        af[i][ks] =
            *(const bf16x8*)&sX[((wave * 2 + i) * 16 + lc) * 64 + ks * 32 + quad * 8];
#pragma unroll
    for (int nb = 0; nb < 8; ++nb)
#pragma unroll
      for (int ks = 0; ks < 2; ++ks) {
        const bf16x8 bb = *(const bf16x8*)&sX[(nb * 16 + lc) * 64 + ks * 32 + quad * 8];
        acc[0][nb] = __builtin_amdgcn_mfma_f32_16x16x32_bf16(af[0][ks], bb, acc[0][nb], 0, 0, 0);
        acc[1][nb] = __builtin_amdgcn_mfma_f32_16x16x32_bf16(af[1][ks], bb, acc[1][nb], 0, 0, 0);
      }
    __syncthreads();
  }
  const float scl = tau[c] * (1.f / 32.f);  // 1/sqrt(1024)
#pragma unroll
  for (int i = 0; i < 2; ++i) {
    const int rbase = (wave * 2 + i) * 16 + quad * 4;
#pragma unroll
    for (int r = 0; r < 4; ++r) {
      const float q2r = sq2[rbase + r];
      float ee[8];
      float ps = 0.f;
#pragma unroll
      for (int nb = 0; nb < 8; ++nb) {
        const float e = __expf((2.f * acc[i][nb][r] - q2r - sq2[nb * 16 + lc]) * scl);
        ee[nb] = e;
        ps += e;
      }
      ps += __shfl_xor(ps, 1);
      ps += __shfl_xor(ps, 2);
      ps += __shfl_xor(ps, 4);
      ps += __shfl_xor(ps, 8);
      const float inv = 1.f / ps;
      u16* Ao = Aout + (size_t)bc * 16384 + (size_t)(rbase + r) * 128;
#pragma unroll
      for (int nb = 0; nb < 8; ++nb) Ao[nb * 16 + lc] = f2b(ee[nb] * inv);
    }
  }
}

// ---------- channel PV: out[b,n,c*128+d] = sum_d' vc[b,n,c*128+d'] * A[d][d'] ----------
__global__ __launch_bounds__(256) void k_chan_pv(const u16* __restrict__ vc,
                                                 const u16* __restrict__ Ac,
                                                 u16* __restrict__ outp) {
  __shared__ u16 sm[8192];
  const int bc = blockIdx.y, b = bc >> 3, c = bc & 7;
  const int m0 = blockIdx.x * 128;
  f32x4 acc[4][4];
#pragma unroll
  for (int i = 0; i < 4; ++i)
#pragma unroll
    for (int j = 0; j < 4; ++j) acc[i][j] = (f32x4){0.f, 0.f, 0.f, 0.f};
  gemm_core_128(vc + ((size_t)b * 1024 + m0) * 1024 + c * 128, Ac + (size_t)bc * 16384,
                1024, 128, 128, sm, acc);
  const int tid = threadIdx.x, wave = tid >> 6;
  const int wr = wave >> 1, wc = wave & 1;
  const int lc = tid & 15, quad = (tid & 63) >> 4;
#pragma unroll
  for (int i = 0; i < 4; ++i)
#pragma unroll
    for (int j = 0; j < 4; ++j)
#pragma unroll
      for (int r = 0; r < 4; ++r)
        outp[((size_t)(b * 1024 + m0 + wr * 64 + i * 16 + quad * 4 + r)) * 1024 + c * 128 +
             wc * 64 + j * 16 + lc] = f2b(acc[i][j][r]);
}

extern "C" void kernel_launch(void* const* d_in, const int* in_sizes, int n_in,
                              void* d_out, int out_size, void* d_ws, size_t ws_size,
                              hipStream_t stream) {
  (void)in_sizes; (void)n_in; (void)out_size; (void)ws_size;
  const float* x = (const float*)d_in[0];
  const float* tau_t = (const float*)d_in[4];
  const float* tau_c = (const float*)d_in[8];
  const float* ln1w = (const float*)d_in[9];
  const float* ln1b = (const float*)d_in[10];
  const float* ln2w = (const float*)d_in[11];
  const float* ln2b = (const float*)d_in[12];
  const float* g1 = (const float*)d_in[13];
  const float* g2 = (const float*)d_in[14];
  float* out = (float*)d_out;

  // workspace carve-up (~62.6 MB total)
  char* p = (char*)d_ws;
  u16* wb[6];
  for (int i = 0; i < 6; ++i) wb[i] = (u16*)(p + (size_t)i * (2u << 20));
  u16* bufA = (u16*)(p + (size_t)12 * (1u << 20));       // 16 MB
  u16* bufQ = bufA + (size_t)8 * 1024 * 1024;            // 16 MB
  u16* bufV = bufQ + (size_t)8 * 1024 * 1024;            // 16 MB
  float* q2b = (float*)(bufV + (size_t)8 * 1024 * 1024); // 512 KB
  float* q2c = q2b + 131072;                             // 32 KB
  u16* Ac = (u16*)(q2c + 8192);                          // 2 MB

  const int widx[6] = {1, 2, 3, 5, 6, 7};  // Wqk_t, Wv_t, Wo_t, Wqk_c, Wv_c, Wo_c
  for (int i = 0; i < 6; ++i)
    k_wtrans<<<dim3(16, 16), 256, 0, stream>>>((const float*)d_in[widx[i]], wb[i]);

  // ---- token diffusion ----
  k_ln<<<8192, 256, 0, stream>>>(x, ln1w, ln1b, bufA);                           // y1
  k_gemm_n<<<dim3(64, 8), 256, 0, stream>>>(bufA, wb[0], bufQ, 1024, 1024, 1024, 1024);  // qk
  k_gemm_t<<<dim3(64, 8), 256, 0, stream>>>(bufA, wb[1], bufV);                  // v^T (B,D,N)
  k_q2<<<2048, 256, 0, stream>>>(bufQ, q2b);
  k_attn<<<dim3(16, 128), 256, 0, stream>>>(bufQ, bufV, q2b, tau_t, bufA);       // attn_out
  k_gemm_res<<<dim3(64, 8), 256, 0, stream>>>(bufA, wb[2], x, g1, out);          // x1 = x + Wo*g1

  // ---- channel diffusion ----
  k_ln<<<8192, 256, 0, stream>>>(out, ln2w, ln2b, bufQ);                         // y2
  k_gemm_t<<<dim3(64, 8), 256, 0, stream>>>(bufQ, wb[3], bufV);                  // qkc^T (B,D,N)
  k_gemm_n<<<dim3(64, 8), 256, 0, stream>>>(bufQ, wb[4], bufA, 1024, 1024, 1024, 1024);  // vc
  k_rowsq<<<2048, 256, 0, stream>>>(bufV, q2c);
  k_chan_s<<<64, 256, 0, stream>>>(bufV, q2c, tau_c, Ac);                        // softmax matrix
  k_chan_pv<<<dim3(8, 64), 256, 0, stream>>>(bufA, Ac, bufQ);                    // chan attn out
  k_gemm_res<<<dim3(64, 8), 256, 0, stream>>>(bufQ, wb[5], out, g2, out);        // out = x1 + Wo*g2
}

// Round 3
// 409.996 us; speedup vs baseline: 1.1353x; 1.1353x over previous
//
#include <hip/hip_runtime.h>

typedef unsigned short u16;
typedef unsigned int u32;
typedef __bf16 bf16x8 __attribute__((ext_vector_type(8)));
typedef _Float16 f16x8 __attribute__((ext_vector_type(8)));
typedef __fp16 fp16x2 __attribute__((ext_vector_type(2)));
typedef float f32x4 __attribute__((ext_vector_type(4)));

__device__ __forceinline__ u16 f2b(float f) {
  u32 u = __float_as_uint(f);
  return (u16)((u + 0x7FFFu + ((u >> 16) & 1u)) >> 16);
}
__device__ __forceinline__ u16 f2h(float f) {
  union { _Float16 h; u16 u; } c;
  c.h = (_Float16)f;
  return c.u;
}
__device__ __forceinline__ u32 pk2h(float a, float b) {
  union { fp16x2 v; u32 u; } c;
  c.v = __builtin_amdgcn_cvt_pkrtz(a, b);
  return c.u;
}
__device__ __forceinline__ float sumsq2(u32 u) {  // bf16 pair
  float lo = __uint_as_float(u << 16);
  float hi = __uint_as_float(u & 0xFFFF0000u);
  return lo * lo + hi * hi;
}
__device__ __forceinline__ float sumsq2h(u32 u) {  // f16 pair
  union { u32 u; _Float16 h[2]; } c;
  c.u = u;
  float lo = (float)c.h[0], hi = (float)c.h[1];
  return lo * lo + hi * hi;
}
__device__ __forceinline__ void gl2lds16(const void* g, void* l) {
  __builtin_amdgcn_global_load_lds((__attribute__((address_space(1))) void*)g,
                                   (__attribute__((address_space(3))) void*)l, 16, 0, 0);
}

// ---------- fused fp32 -> bf16 transposed weights (all 6 in one launch) ----------
struct W6 {
  const float* src[6];
  u16* dst[6];
};
__global__ __launch_bounds__(256) void k_wtrans6(W6 p) {
  const float* __restrict__ W = p.src[blockIdx.z];
  u16* __restrict__ Wt = p.dst[blockIdx.z];
  __shared__ float sm[64 * 65];
  const int r0 = blockIdx.y * 64, c0 = blockIdx.x * 64;
  const int tid = threadIdx.x;
#pragma unroll
  for (int i = 0; i < 16; ++i) {
    int idx = i * 256 + tid;
    int r = idx >> 6, c = idx & 63;
    sm[c * 65 + r] = W[(size_t)(r0 + r) * 1024 + c0 + c];
  }
  __syncthreads();
#pragma unroll
  for (int i = 0; i < 16; ++i) {
    int idx = i * 256 + tid;
    int r = idx >> 6, c = idx & 63;
    Wt[(size_t)(c0 + r) * 1024 + r0 + c] = f2b(sm[r * 65 + c]);
  }
}

// ---------- layernorm fp32 -> bf16 ----------
__global__ __launch_bounds__(256) void k_ln(const float* __restrict__ x,
                                            const float* __restrict__ w,
                                            const float* __restrict__ bb,
                                            u16* __restrict__ y) {
  const int row = blockIdx.x;
  const int tid = threadIdx.x;
  const float4 v = ((const float4*)(x + (size_t)row * 1024))[tid];
  float s = v.x + v.y + v.z + v.w;
  float s2 = v.x * v.x + v.y * v.y + v.z * v.z + v.w * v.w;
  for (int o = 32; o > 0; o >>= 1) {
    s += __shfl_down(s, o);
    s2 += __shfl_down(s2, o);
  }
  __shared__ float red[8];
  const int wave = tid >> 6;
  if ((tid & 63) == 0) { red[wave * 2] = s; red[wave * 2 + 1] = s2; }
  __syncthreads();
  s = red[0] + red[2] + red[4] + red[6];
  s2 = red[1] + red[3] + red[5] + red[7];
  const float mu = s * (1.0f / 1024.0f);
  const float var = s2 * (1.0f / 1024.0f) - mu * mu;
  const float rs = rsqrtf(var + 1e-5f);
  const float4 wv = ((const float4*)w)[tid];
  const float4 bv = ((const float4*)bb)[tid];
  u16* yr = y + (size_t)row * 1024 + tid * 4;
  yr[0] = f2b((v.x - mu) * rs * wv.x + bv.x);
  yr[1] = f2b((v.y - mu) * rs * wv.y + bv.y);
  yr[2] = f2b((v.z - mu) * rs * wv.z + bv.z);
  yr[3] = f2b((v.w - mu) * rs * wv.w + bv.w);
}

// ---------- per-head sum of squares of qk rows (token path, bf16 input) ----------
__global__ __launch_bounds__(256) void k_q2(const u16* __restrict__ qk,
                                            float* __restrict__ q2) {
  const int row = blockIdx.x * 4 + (threadIdx.x >> 6);
  const int lane = threadIdx.x & 63;
  const u16* p = qk + (size_t)row * 1024 + lane * 16;
  const uint4 a = *(const uint4*)p;
  const uint4 b = *(const uint4*)(p + 8);
  float s = sumsq2(a.x) + sumsq2(a.y) + sumsq2(a.z) + sumsq2(a.w) +
            sumsq2(b.x) + sumsq2(b.y) + sumsq2(b.z) + sumsq2(b.w);
  s += __shfl_down(s, 1, 4);
  s += __shfl_down(s, 2, 4);
  if ((lane & 3) == 0) {
    const int h = lane >> 2;
    const int bidx = row >> 10, n = row & 1023;
    q2[((size_t)(bidx * 16 + h)) * 1024 + n] = s;
  }
}

// ---------- full-row sum of squares (channel path, f16 input) ----------
__global__ __launch_bounds__(256) void k_rowsq(const u16* __restrict__ M,
                                               float* __restrict__ out) {
  const int row = blockIdx.x * 4 + (threadIdx.x >> 6);
  const int lane = threadIdx.x & 63;
  const u16* p = M + (size_t)row * 1024 + lane * 16;
  const uint4 a = *(const uint4*)p;
  const uint4 b = *(const uint4*)(p + 8);
  float s = sumsq2h(a.x) + sumsq2h(a.y) + sumsq2h(a.z) + sumsq2h(a.w) +
            sumsq2h(b.x) + sumsq2h(b.y) + sumsq2h(b.z) + sumsq2h(b.w);
  for (int o = 32; o > 0; o >>= 1) s += __shfl_down(s, o);
  if (lane == 0) out[row] = s;
}

// ---------- 128x128-tile bf16 MFMA GEMM core (B^T layout, m97 structure) ----------
__device__ __forceinline__ void gemm_core_128(const u16* __restrict__ Ab,
                                              const u16* __restrict__ Bb,
                                              int lda, int ldb, int K,
                                              u16* sm, f32x4 acc[4][4]) {
  const int tid = threadIdx.x;
  const int wave = tid >> 6;
  const int wr = wave >> 1, wc = wave & 1;
  const int lane = tid & 63;
  const int lc = lane & 15, quad = lane >> 4;
  u16* smA = sm;
  u16* smB = sm + 4096;
  const int sr = tid >> 2, sk = (tid & 3) << 3;
  const u16* gA = Ab + (size_t)sr * lda + sk;
  const u16* gB = Bb + (size_t)sr * ldb + sk;
  const size_t a64 = (size_t)64 * lda, b64 = (size_t)64 * ldb;
  u16* dA = smA + tid * 8;
  u16* dB = smB + tid * 8;
  for (int kt = 0; kt < K; kt += 32) {
    gl2lds16(gA + kt, dA);
    gl2lds16(gA + a64 + kt, dA + 2048);
    gl2lds16(gB + kt, dB);
    gl2lds16(gB + b64 + kt, dB + 2048);
    __syncthreads();
    bf16x8 af[4], bfr[4];
#pragma unroll
    for (int i = 0; i < 4; ++i) {
      af[i] = *(const bf16x8*)(smA + (wr * 64 + i * 16 + lc) * 32 + quad * 8);
      bfr[i] = *(const bf16x8*)(smB + (wc * 64 + i * 16 + lc) * 32 + quad * 8);
    }
#pragma unroll
    for (int i = 0; i < 4; ++i)
#pragma unroll
      for (int j = 0; j < 4; ++j)
        acc[i][j] = __builtin_amdgcn_mfma_f32_16x16x32_bf16(af[i], bfr[j], acc[i][j], 0, 0, 0);
    __syncthreads();
  }
}

// ---------- GEMM, bf16 output in natural row-major ----------
__global__ __launch_bounds__(256) void k_gemm_n(const u16* __restrict__ A,
                                                const u16* __restrict__ Bt,
                                                u16* __restrict__ C,
                                                int lda, int ldb, int ldc, int K) {
  __shared__ u16 sm[8192];
  const int m0 = blockIdx.x * 128, n0 = blockIdx.y * 128;
  f32x4 acc[4][4];
#pragma unroll
  for (int i = 0; i < 4; ++i)
#pragma unroll
    for (int j = 0; j < 4; ++j) acc[i][j] = (f32x4){0.f, 0.f, 0.f, 0.f};
  gemm_core_128(A + (size_t)m0 * lda, Bt + (size_t)n0 * ldb, lda, ldb, K, sm, acc);
  const int tid = threadIdx.x, wave = tid >> 6;
  const int wr = wave >> 1, wc = wave & 1;
  const int lc = tid & 15, quad = (tid & 63) >> 4;
#pragma unroll
  for (int i = 0; i < 4; ++i)
#pragma unroll
    for (int j = 0; j < 4; ++j) {
      const int n = n0 + wc * 64 + j * 16 + lc;
#pragma unroll
      for (int r = 0; r < 4; ++r) {
        const int m = m0 + wr * 64 + i * 16 + quad * 4 + r;
        C[(size_t)m * ldc + n] = f2b(acc[i][j][r]);
      }
    }
}

// ---------- GEMM + residual epilogue: out = res + acc*gamma[n] (fp32) ----------
__global__ __launch_bounds__(256) void k_gemm_res(const u16* __restrict__ A,
                                                  const u16* __restrict__ Bt,
                                                  const float* __restrict__ res,
                                                  const float* __restrict__ gamma,
                                                  float* __restrict__ out) {
  __shared__ u16 sm[8192];
  const int m0 = blockIdx.x * 128, n0 = blockIdx.y * 128;
  f32x4 acc[4][4];
#pragma unroll
  for (int i = 0; i < 4; ++i)
#pragma unroll
    for (int j = 0; j < 4; ++j) acc[i][j] = (f32x4){0.f, 0.f, 0.f, 0.f};
  gemm_core_128(A + (size_t)m0 * 1024, Bt + (size_t)n0 * 1024, 1024, 1024, 1024, sm, acc);
  const int tid = threadIdx.x, wave = tid >> 6;
  const int wr = wave >> 1, wc = wave & 1;
  const int lc = tid & 15, quad = (tid & 63) >> 4;
#pragma unroll
  for (int i = 0; i < 4; ++i)
#pragma unroll
    for (int j = 0; j < 4; ++j) {
      const int n = n0 + wc * 64 + j * 16 + lc;
      const float g = gamma[n];
#pragma unroll
      for (int r = 0; r < 4; ++r) {
        const size_t idx = (size_t)(m0 + wr * 64 + i * 16 + quad * 4 + r) * 1024 + n;
        out[idx] = res[idx] + acc[i][j][r] * g;
      }
    }
}

// ---------- GEMM, f16 output transposed per batch: outT[(b*1024+n)*1024 + mloc] ----------
__global__ __launch_bounds__(256) void k_gemm_t(const u16* __restrict__ A,
                                                const u16* __restrict__ Bt,
                                                u16* __restrict__ outT) {
  __shared__ u16 sm[8704];
  const int m0 = blockIdx.x * 128, n0 = blockIdx.y * 128;
  f32x4 acc[4][4];
#pragma unroll
  for (int i = 0; i < 4; ++i)
#pragma unroll
    for (int j = 0; j < 4; ++j) acc[i][j] = (f32x4){0.f, 0.f, 0.f, 0.f};
  gemm_core_128(A + (size_t)m0 * 1024, Bt + (size_t)n0 * 1024, 1024, 1024, 1024, sm, acc);
  const int tid = threadIdx.x, wave = tid >> 6;
  const int wr = wave >> 1, wc = wave & 1;
  const int lc = tid & 15, quad = (tid & 63) >> 4;
  const int b = m0 >> 10, mloc = m0 & 1023;
  for (int half = 0; half < 2; ++half) {
    if (wc == half) {
#pragma unroll
      for (int i = 0; i < 4; ++i)
#pragma unroll
        for (int j = 0; j < 4; ++j)
#pragma unroll
          for (int r = 0; r < 4; ++r)
            sm[(j * 16 + lc) * 136 + wr * 64 + i * 16 + quad * 4 + r] = f2h(acc[i][j][r]);
    }
    __syncthreads();
#pragma unroll
    for (int it = 0; it < 4; ++it) {
      const int rr = it * 16 + (tid >> 4);
      const int c8 = (tid & 15) << 3;
      *(uint4*)&outT[((size_t)(b * 1024 + n0 + half * 64 + rr)) * 1024 + mloc + c8] =
          *(const uint4*)&sm[rr * 136 + c8];
    }
    __syncthreads();
  }
}

// ---------- token attention: S^T trick, f16 P*V, 34KB LDS, 4 blocks/CU ----------
__global__ __launch_bounds__(256, 4) void k_attn(const u16* __restrict__ qk,   // bf16
                                                 const u16* __restrict__ vT,   // f16 (B,D,N)
                                                 const float* __restrict__ q2,
                                                 const float* __restrict__ tau,
                                                 u16* __restrict__ outp) {
  const int q0 = blockIdx.x * 64;
  const int bh = blockIdx.y;
  const int b = bh >> 4, h = bh & 15;
  __shared__ u16 sQ[4096];      // [64 q][64 d] bf16, swizzled chunks
  __shared__ u16 sK[4096];      // [64 k][64 d] bf16, swizzled chunks
  __shared__ u16 sV[4096];      // [64 d][64 n] f16,  swizzled chunks
  __shared__ u16 sP[64 * 72];   // [q][k] f16, padded
  __shared__ float sInv[64];
  const int tid = threadIdx.x;
  const int wave = tid >> 6;
  const int lane = tid & 63;
  const int lc = lane & 15, quad = lane >> 4;
  const int sw = lc & 7;        // xor swizzle key for fragment reads
  const float scale = tau[h] * 0.125f;  // 1/sqrt(64)
  const float two_scale = 2.0f * scale;
  const u16* qkb = qk + (size_t)b * (1024 * 1024) + h * 64;
  const u16* vTb = vT + ((size_t)b * 1024 + h * 64) * 1024;
  const float* q2g = q2 + (size_t)bh * 1024;

  // staging: LDS chunk ci <- global chunk (row=ci>>3, col=(ci&7)^(row&7))
  const int r0 = tid >> 3, c0s = (tid & 7) ^ (r0 & 7);
  const int r1 = r0 + 32, c1s = (tid & 7) ^ (r1 & 7);

  gl2lds16(qkb + (size_t)(q0 + r0) * 1024 + c0s * 8, sQ + tid * 8);
  gl2lds16(qkb + (size_t)(q0 + r1) * 1024 + c1s * 8, sQ + 2048 + tid * 8);
  const int qrow = wave * 16 + lc;
  const float tq_s = q2g[q0 + qrow] * scale;

  f32x4 oacc[4];
#pragma unroll
  for (int j = 0; j < 4; ++j) oacc[j] = (f32x4){0.f, 0.f, 0.f, 0.f};
  float rs = 0.f;

  for (int kt = 0; kt < 16; ++kt) {
    __syncthreads();  // (A) everyone done reading sK/sV from prev iter
    const int kbase = kt * 64;
    gl2lds16(qkb + (size_t)(kbase + r0) * 1024 + c0s * 8, sK + tid * 8);
    gl2lds16(qkb + (size_t)(kbase + r1) * 1024 + c1s * 8, sK + 2048 + tid * 8);
    gl2lds16(vTb + (size_t)r0 * 1024 + kbase + c0s * 8, sV + tid * 8);
    gl2lds16(vTb + (size_t)r1 * 1024 + kbase + c1s * 8, sV + 2048 + tid * 8);
    __syncthreads();  // (B) loads landed (vmcnt drained by barrier)

    // Q fragments (B-operand): rows q, k-contiguous
    const bf16x8 aq0 = *(const bf16x8*)(sQ + (qrow * 8 + (quad ^ sw)) * 8);
    const bf16x8 aq1 = *(const bf16x8*)(sQ + (qrow * 8 + ((4 + quad) ^ sw)) * 8);

    // S^T = K * Q^T : C rows = k, cols = q
    f32x4 s[4];
#pragma unroll
    for (int nb = 0; nb < 4; ++nb) {
      const int krow = nb * 16 + lc;
      const bf16x8 bk0 = *(const bf16x8*)(sK + (krow * 8 + (quad ^ sw)) * 8);
      const bf16x8 bk1 = *(const bf16x8*)(sK + (krow * 8 + ((4 + quad) ^ sw)) * 8);
      f32x4 z = (f32x4){0.f, 0.f, 0.f, 0.f};
      z = __builtin_amdgcn_mfma_f32_16x16x32_bf16(bk0, aq0, z, 0, 0, 0);
      s[nb] = __builtin_amdgcn_mfma_f32_16x16x32_bf16(bk1, aq1, z, 0, 0, 0);
    }
    // exp + pack f16 + write P rows (wave-local region of sP) + row-sum partials
#pragma unroll
    for (int nb = 0; nb < 4; ++nb) {
      const float4 tk4 = *(const float4*)(q2g + kbase + nb * 16 + quad * 4);
      const float e0 = __expf(fmaf(s[nb][0], two_scale, -fmaf(tk4.x, scale, tq_s)));
      const float e1 = __expf(fmaf(s[nb][1], two_scale, -fmaf(tk4.y, scale, tq_s)));
      const float e2 = __expf(fmaf(s[nb][2], two_scale, -fmaf(tk4.z, scale, tq_s)));
      const float e3 = __expf(fmaf(s[nb][3], two_scale, -fmaf(tk4.w, scale, tq_s)));
      const u32 p01 = pk2h(e0, e1);
      const u32 p23 = pk2h(e2, e3);
      *(uint2*)&sP[qrow * 72 + nb * 16 + quad * 4] = make_uint2(p01, p23);
      rs += (e0 + e1) + (e2 + e3);
    }
    // P * V (A = own P rows, B = V^T rows)
    const f16x8 ap0 = *(const f16x8*)&sP[qrow * 72 + quad * 8];
    const f16x8 ap1 = *(const f16x8*)&sP[qrow * 72 + 32 + quad * 8];
#pragma unroll
    for (int j2 = 0; j2 < 4; ++j2) {
      const int drow = j2 * 16 + lc;
      const f16x8 bv0 = *(const f16x8*)(sV + (drow * 8 + (quad ^ sw)) * 8);
      const f16x8 bv1 = *(const f16x8*)(sV + (drow * 8 + ((4 + quad) ^ sw)) * 8);
      oacc[j2] = __builtin_amdgcn_mfma_f32_16x16x32_f16(ap0, bv0, oacc[j2], 0, 0, 0);
      oacc[j2] = __builtin_amdgcn_mfma_f32_16x16x32_f16(ap1, bv1, oacc[j2], 0, 0, 0);
    }
  }
  // finalize row sums: reduce across quads (k partitions)
  rs += __shfl_xor(rs, 16);
  rs += __shfl_xor(rs, 32);
  if (lane < 16) sInv[wave * 16 + lane] = 1.f / rs;
#pragma unroll
  for (int r = 0; r < 4; ++r) {
    const int row = wave * 16 + quad * 4 + r;
    const float inv = sInv[row];
    u16* o = outp + ((size_t)(b * 1024 + q0 + row)) * 1024 + h * 64;
#pragma unroll
    for (int j2 = 0; j2 < 4; ++j2) o[j2 * 16 + lc] = f2b(oacc[j2][r] * inv);
  }
}

// ---------- channel attention matrix: A = softmax over d' of scaled (X^T X), f16 input ----------
__global__ __launch_bounds__(256) void k_chan_s(const u16* __restrict__ qkcT,  // f16
                                                const float* __restrict__ q2c,
                                                const float* __restrict__ tau,
                                                u16* __restrict__ Aout) {      // bf16
  const int bc = blockIdx.x, b = bc >> 3, c = bc & 7;
  __shared__ u16 sX[8192];
  __shared__ float sq2[128];
  const int tid = threadIdx.x, wave = tid >> 6, lane = tid & 63;
  const int lc = lane & 15, quad = lane >> 4;
  const u16* Xb = qkcT + ((size_t)b * 1024 + c * 128) * 1024;
  if (tid < 128) sq2[tid] = q2c[(size_t)b * 1024 + c * 128 + tid];
  f32x4 acc[2][8];
#pragma unroll
  for (int i = 0; i < 2; ++i)
#pragma unroll
    for (int j = 0; j < 8; ++j) acc[i][j] = (f32x4){0.f, 0.f, 0.f, 0.f};
  for (int nt = 0; nt < 1024; nt += 64) {
#pragma unroll
    for (int i = 0; i < 4; ++i) {
      const int idx = i * 256 + tid;
      gl2lds16(Xb + (size_t)(idx >> 3) * 1024 + nt + ((idx & 7) << 3), sX + idx * 8);
    }
    __syncthreads();
    f16x8 af[2][2];
#pragma unroll
    for (int i = 0; i < 2; ++i)
#pragma unroll
      for (int ks = 0; ks < 2; ++ks)
        af[i][ks] =
            *(const f16x8*)&sX[((wave * 2 + i) * 16 + lc) * 64 + ks * 32 + quad * 8];
#pragma unroll
    for (int nb = 0; nb < 8; ++nb)
#pragma unroll
      for (int ks = 0; ks < 2; ++ks) {
        const f16x8 bb = *(const f16x8*)&sX[(nb * 16 + lc) * 64 + ks * 32 + quad * 8];
        acc[0][nb] = __builtin_amdgcn_mfma_f32_16x16x32_f16(af[0][ks], bb, acc[0][nb], 0, 0, 0);
        acc[1][nb] = __builtin_amdgcn_mfma_f32_16x16x32_f16(af[1][ks], bb, acc[1][nb], 0, 0, 0);
      }
    __syncthreads();
  }
  const float scl = tau[c] * (1.f / 32.f);  // 1/sqrt(1024)
#pragma unroll
  for (int i = 0; i < 2; ++i) {
    const int rbase = (wave * 2 + i) * 16 + quad * 4;
#pragma unroll
    for (int r = 0; r < 4; ++r) {
      const float q2r = sq2[rbase + r];
      float ee[8];
      float ps = 0.f;
#pragma unroll
      for (int nb = 0; nb < 8; ++nb) {
        const float e = __expf((2.f * acc[i][nb][r] - q2r - sq2[nb * 16 + lc]) * scl);
        ee[nb] = e;
        ps += e;
      }
      ps += __shfl_xor(ps, 1);
      ps += __shfl_xor(ps, 2);
      ps += __shfl_xor(ps, 4);
      ps += __shfl_xor(ps, 8);
      const float inv = 1.f / ps;
      u16* Ao = Aout + (size_t)bc * 16384 + (size_t)(rbase + r) * 128;
#pragma unroll
      for (int nb = 0; nb < 8; ++nb) Ao[nb * 16 + lc] = f2b(ee[nb] * inv);
    }
  }
}

// ---------- channel PV: out[b,n,c*128+d] = sum_d' vc[b,n,c*128+d'] * A[d][d'] ----------
__global__ __launch_bounds__(256) void k_chan_pv(const u16* __restrict__ vc,
                                                 const u16* __restrict__ Ac,
                                                 u16* __restrict__ outp) {
  __shared__ u16 sm[8192];
  const int bc = blockIdx.y, b = bc >> 3, c = bc & 7;
  const int m0 = blockIdx.x * 128;
  f32x4 acc[4][4];
#pragma unroll
  for (int i = 0; i < 4; ++i)
#pragma unroll
    for (int j = 0; j < 4; ++j) acc[i][j] = (f32x4){0.f, 0.f, 0.f, 0.f};
  gemm_core_128(vc + ((size_t)b * 1024 + m0) * 1024 + c * 128, Ac + (size_t)bc * 16384,
                1024, 128, 128, sm, acc);
  const int tid = threadIdx.x, wave = tid >> 6;
  const int wr = wave >> 1, wc = wave & 1;
  const int lc = tid & 15, quad = (tid & 63) >> 4;
#pragma unroll
  for (int i = 0; i < 4; ++i)
#pragma unroll
    for (int j = 0; j < 4; ++j)
#pragma unroll
      for (int r = 0; r < 4; ++r)
        outp[((size_t)(b * 1024 + m0 + wr * 64 + i * 16 + quad * 4 + r)) * 1024 + c * 128 +
             wc * 64 + j * 16 + lc] = f2b(acc[i][j][r]);
}

extern "C" void kernel_launch(void* const* d_in, const int* in_sizes, int n_in,
                              void* d_out, int out_size, void* d_ws, size_t ws_size,
                              hipStream_t stream) {
  (void)in_sizes; (void)n_in; (void)out_size; (void)ws_size;
  const float* x = (const float*)d_in[0];
  const float* tau_t = (const float*)d_in[4];
  const float* tau_c = (const float*)d_in[8];
  const float* ln1w = (const float*)d_in[9];
  const float* ln1b = (const float*)d_in[10];
  const float* ln2w = (const float*)d_in[11];
  const float* ln2b = (const float*)d_in[12];
  const float* g1 = (const float*)d_in[13];
  const float* g2 = (const float*)d_in[14];
  float* out = (float*)d_out;

  // workspace carve-up (~62.6 MB total)
  char* p = (char*)d_ws;
  u16* wb[6];
  for (int i = 0; i < 6; ++i) wb[i] = (u16*)(p + (size_t)i * (2u << 20));
  u16* bufA = (u16*)(p + (size_t)12 * (1u << 20));       // 16 MB
  u16* bufQ = bufA + (size_t)8 * 1024 * 1024;            // 16 MB
  u16* bufV = bufQ + (size_t)8 * 1024 * 1024;            // 16 MB
  float* q2b = (float*)(bufV + (size_t)8 * 1024 * 1024); // 512 KB
  float* q2c = q2b + 131072;                             // 32 KB
  u16* Ac = (u16*)(q2c + 8192);                          // 2 MB

  W6 w6;
  const int widx[6] = {1, 2, 3, 5, 6, 7};  // Wqk_t, Wv_t, Wo_t, Wqk_c, Wv_c, Wo_c
  for (int i = 0; i < 6; ++i) { w6.src[i] = (const float*)d_in[widx[i]]; w6.dst[i] = wb[i]; }
  k_wtrans6<<<dim3(16, 16, 6), 256, 0, stream>>>(w6);

  // ---- token diffusion ----
  k_ln<<<8192, 256, 0, stream>>>(x, ln1w, ln1b, bufA);                           // y1 (bf16)
  k_gemm_n<<<dim3(64, 8), 256, 0, stream>>>(bufA, wb[0], bufQ, 1024, 1024, 1024, 1024);  // qk bf16
  k_gemm_t<<<dim3(64, 8), 256, 0, stream>>>(bufA, wb[1], bufV);                  // v^T f16 (B,D,N)
  k_q2<<<2048, 256, 0, stream>>>(bufQ, q2b);
  k_attn<<<dim3(16, 128), 256, 0, stream>>>(bufQ, bufV, q2b, tau_t, bufA);       // attn_out bf16
  k_gemm_res<<<dim3(64, 8), 256, 0, stream>>>(bufA, wb[2], x, g1, out);          // x1 = x + Wo*g1

  // ---- channel diffusion ----
  k_ln<<<8192, 256, 0, stream>>>(out, ln2w, ln2b, bufQ);                         // y2 (bf16)
  k_gemm_t<<<dim3(64, 8), 256, 0, stream>>>(bufQ, wb[3], bufV);                  // qkc^T f16 (B,D,N)
  k_gemm_n<<<dim3(64, 8), 256, 0, stream>>>(bufQ, wb[4], bufA, 1024, 1024, 1024, 1024);  // vc bf16
  k_rowsq<<<2048, 256, 0, stream>>>(bufV, q2c);
  k_chan_s<<<64, 256, 0, stream>>>(bufV, q2c, tau_c, Ac);                        // softmax matrix bf16
  k_chan_pv<<<dim3(8, 64), 256, 0, stream>>>(bufA, Ac, bufQ);                    // chan attn out bf16
  k_gemm_res<<<dim3(64, 8), 256, 0, stream>>>(bufQ, wb[5], out, g2, out);        // out = x1 + Wo*g2
}